// Round 11
// baseline (42.327 us; speedup 1.0000x reference)
//
#include <hip/hip_runtime.h>
#include <hip/hip_bf16.h>
#include <math.h>

// Shapes:
//   input [32,1024] f32; source_hids [2048,32,1024] f32 (256 MiB);
//   encoder_padding_mask [2048,32] bool; W_in [1024,1024]; W_out [1024,2048]
// Outputs flat: output [32,1024], beta [2048,32], alpha [2048,32]
//
// Exact simplifications (rounds 1-2):
//   alpha = p * exclusive_cumprod(1-p); beta = alpha.
//   f32: sigmoid(e)==1.0f exactly for e >~ 17.3 => (1-p)==0.0f => running
//   cumprod hits EXACT 0 => all later beta exactly 0 regardless of p.
//   => energy/scan only for s < CH=64; tails pre-zeroed; exact sequential
//   fallback (P ~ 1e-9) finishes a non-collapsed column.
//
// Round-11: remove one sequential phase WITHOUT narrowing (R8: grid.sync
// disastrous; R9: narrow fusion loses; R10: work-shuffling zero-sum =>
// each phase has a ~5-7us launch+ramp floor). K1's xproj waves already hold
// x[b, i0:i0+16] in registers; they immediately compute 16-dim partial
// energies for all 64 s (lane=s, coalesced epart write). K3's scan sums the
// 64 chunk partials (L2-hot, fixed order => deterministic, no atomics).
// 3 wide phases: K1 (xproj+epart+tailfill) -> K3 (scan+wc) -> K4 (out).

#define SRC_LEN 2048
#define BSZ     32
#define DIM     1024
#define CH      64
#define TAIL4   ((SRC_LEN - CH) * BSZ / 4)   // 15872 float4 per tail array
#define XPB     512                          // xproj blocks (2048 waves)
#define FILLB   (TAIL4 / 256)                // 62 tail-fill blocks
#define NB1     (XPB + FILLB)

// ---------------- kernel 1: xproj + energy partials + tail fill ----------------
__global__ __launch_bounds__(256) void k_front(const float* __restrict__ input,
                                               const float* __restrict__ W_in,
                                               const float* __restrict__ src,
                                               float* __restrict__ x,
                                               float* __restrict__ epart,
                                               float* __restrict__ beta_out,
                                               float* __restrict__ alpha_out) {
    int bid = blockIdx.x;
    int t = threadIdx.x;
    int lane = t & 63;
    if (bid < XPB) {
        // x = input @ W_in^T ; wave -> (b, 16-wide i-chunk)
        int wid = bid * 4 + (t >> 6);             // 0..2047
        int b   = wid >> 6;                       // 0..31
        int ic  = wid & 63;                       // i-chunk 0..63
        int i0  = ic * 16;
        const float4* inp = (const float4*)(input + (size_t)b * DIM);
        float4 in[4];
        #pragma unroll
        for (int k = 0; k < 4; ++k) in[k] = inp[lane + 64 * k];
        float accs[16];
        #pragma unroll 4
        for (int i = 0; i < 16; ++i) {
            const float4* wr = (const float4*)(W_in + (size_t)(i0 + i) * DIM);
            float acc = 0.f;
            #pragma unroll
            for (int k = 0; k < 4; ++k) {
                float4 wv = wr[lane + 64 * k];
                acc += wv.x * in[k].x + wv.y * in[k].y + wv.z * in[k].z + wv.w * in[k].w;
            }
            #pragma unroll
            for (int off = 32; off; off >>= 1) acc += __shfl_down(acc, off);
            accs[i] = acc;                        // full sum lives in lane 0
            if (lane == 0) x[(size_t)b * DIM + i0 + i] = acc;
        }
        // partial energies over this 16-dim slice, for all 64 s; lane = s
        const float4* sp = (const float4*)(src + ((size_t)lane * BSZ + b) * DIM + i0);
        float pe = 0.f;
        #pragma unroll
        for (int k = 0; k < 4; ++k) {
            float4 v = sp[k];
            pe += v.x * __shfl(accs[4 * k + 0], 0)
                + v.y * __shfl(accs[4 * k + 1], 0)
                + v.z * __shfl(accs[4 * k + 2], 0)
                + v.w * __shfl(accs[4 * k + 3], 0);
        }
        // epart[ic][b][s] — coalesced 64-float write per wave
        epart[(size_t)ic * (BSZ * CH) + b * CH + lane] = pe;
    } else {
        // coalesced float4 zero-fill of beta/alpha tails
        int i = (bid - XPB) * 256 + t;            // < TAIL4 by construction
        float4 z = {0.f, 0.f, 0.f, 0.f};
        ((float4*)(beta_out  + (size_t)CH * BSZ))[i] = z;
        ((float4*)(alpha_out + (size_t)CH * BSZ))[i] = z;
    }
}

// ---------------- kernel 2: scan + wc (+ exact sequential fallback) ----------------
// 32 blocks (one per b), 1024 threads; reads are L2/L3-hot.
__global__ __launch_bounds__(1024) void k_scan_wc(const float* __restrict__ src,
                                                  const float* __restrict__ x,
                                                  const unsigned char* __restrict__ mask,
                                                  const float* __restrict__ epart,
                                                  float* __restrict__ beta_out,
                                                  float* __restrict__ alpha_out,
                                                  float* __restrict__ wc) {
    int b = blockIdx.x;
    int t = threadIdx.x;
    int w = t >> 6, lane = t & 63;
    __shared__ float pb[CH];
    __shared__ int   snz;      // number of leading rows with beta != 0
    __shared__ float cstate;
    __shared__ float red[16];
    __shared__ float crun, bcur;
    __shared__ __align__(16) float xs[DIM];

    // wave 0: sum energy partials (fixed order), sigmoid + exclusive cumprod scan
    if (w == 0) {
        float ev = 0.f;
        #pragma unroll
        for (int c = 0; c < 64; ++c)
            ev += epart[(size_t)c * (BSZ * CH) + b * CH + lane];
        if (mask[(size_t)lane * BSZ + b]) ev = -1e9f;
        float p  = 1.0f / (1.0f + expf(-ev));
        float om = 1.0f - p;
        float prod = om;
        #pragma unroll
        for (int off = 1; off < 64; off <<= 1) {
            float o = __shfl_up(prod, off);
            if (lane >= off) prod *= o;
        }
        float excl = __shfl_up(prod, 1);
        if (lane == 0) excl = 1.0f;
        float a = p * excl;
        beta_out[(size_t)lane * BSZ + b]  = a;
        alpha_out[(size_t)lane * BSZ + b] = a;
        pb[lane] = a;
        unsigned long long nz = __ballot(a != 0.0f);
        if (lane == 0) snz = (nz == 0ULL) ? 0 : (64 - __builtin_clzll(nz));
        if (lane == 63) cstate = prod;
    }
    __syncthreads();

    // weighted context over the nonzero prefix (rows cache-hot)
    float acc = 0.f;                       // thread t owns wc[b, t]
    int smax = snz;
    for (int s = 0; s < smax; ++s) {
        float wgt = pb[s];
        if (wgt != 0.0f) acc += wgt * src[((size_t)s * BSZ + b) * DIM + t];
    }

    // sequential fallback for a non-collapsed column (exact; ~never runs)
    if (cstate != 0.0f) {
        for (int i = t; i < DIM; i += 1024) xs[i] = x[(size_t)b * DIM + i];
        if (t == 0) crun = cstate;
        __syncthreads();
        for (int s = CH; s < SRC_LEN; ++s) {
            float v = src[((size_t)s * BSZ + b) * DIM + t];
            float part = v * xs[t];
            #pragma unroll
            for (int off = 32; off; off >>= 1) part += __shfl_down(part, off);
            if (lane == 0) red[w] = part;
            __syncthreads();
            if (t == 0) {
                float ev = 0.f;
                #pragma unroll
                for (int i = 0; i < 16; ++i) ev += red[i];
                if (mask[(size_t)s * BSZ + b]) ev = -1e9f;
                float p = 1.0f / (1.0f + expf(-ev));
                float a = p * crun;
                beta_out[(size_t)s * BSZ + b]  = a;
                alpha_out[(size_t)s * BSZ + b] = a;
                bcur = a;
                crun = crun * (1.0f - p);
            }
            __syncthreads();
            acc += bcur * v;
            if (crun == 0.0f) break;
        }
    }

    wc[(size_t)b * DIM + t] = acc;
}

// ---------------- kernel 3: out = tanh([wc, input] @ W_out^T) (register GEMV) ----------------
// 512 blocks x 256 thr = 2048 waves; wave -> (b, 16-wide o-chunk); Q=1.
__global__ __launch_bounds__(256) void k_out(const float* __restrict__ wc,
                                             const float* __restrict__ input,
                                             const float* __restrict__ W,
                                             float* __restrict__ out) {
    int wid  = blockIdx.x * 4 + (threadIdx.x >> 6);   // 0..2047
    int lane = threadIdx.x & 63;
    int b    = wid >> 6;                              // 0..31
    int o0   = (wid & 63) * 16;                       // 0..1008
    const float4* wcp = (const float4*)(wc    + (size_t)b * DIM);
    const float4* inp = (const float4*)(input + (size_t)b * DIM);
    float4 c[4], u[4];
    #pragma unroll
    for (int k = 0; k < 4; ++k) {
        c[k] = wcp[lane + 64 * k];
        u[k] = inp[lane + 64 * k];
    }
    #pragma unroll 4
    for (int i = 0; i < 16; ++i) {
        const float4* wr = (const float4*)(W + (size_t)(o0 + i) * 2 * DIM);
        float acc = 0.f;
        #pragma unroll
        for (int k = 0; k < 4; ++k) {
            float4 wv = wr[lane + 64 * k];            // pairs with wc part
            acc += wv.x * c[k].x + wv.y * c[k].y + wv.z * c[k].z + wv.w * c[k].w;
        }
        #pragma unroll
        for (int k = 0; k < 4; ++k) {
            float4 wv = wr[256 + lane + 64 * k];      // pairs with input part
            acc += wv.x * u[k].x + wv.y * u[k].y + wv.z * u[k].z + wv.w * u[k].w;
        }
        #pragma unroll
        for (int off = 32; off; off >>= 1) acc += __shfl_down(acc, off);
        if (lane == 0) out[(size_t)b * DIM + o0 + i] = tanhf(acc);
    }
}

extern "C" void kernel_launch(void* const* d_in, const int* in_sizes, int n_in,
                              void* d_out, int out_size, void* d_ws, size_t ws_size,
                              hipStream_t stream) {
    const float* input = (const float*)d_in[0];
    const float* src   = (const float*)d_in[1];
    const unsigned char* mask = (const unsigned char*)d_in[2];
    const float* W_in  = (const float*)d_in[3];
    const float* W_out = (const float*)d_in[4];

    float* out_proj  = (float*)d_out;                 // [32,1024]
    float* beta_out  = out_proj + BSZ * DIM;          // [2048,32]
    float* alpha_out = beta_out + SRC_LEN * BSZ;      // [2048,32]

    float* ws = (float*)d_ws;
    float* x     = ws;                     // 32768 floats
    float* wc    = x + BSZ * DIM;          // 32768 floats
    float* epart = wc + BSZ * DIM;         // 64*32*64 = 131072 floats

    k_front<<<NB1, 256, 0, stream>>>(input, W_in, src, x, epart, beta_out, alpha_out);
    k_scan_wc<<<BSZ, 1024, 0, stream>>>(src, x, mask, epart, beta_out, alpha_out, wc);
    k_out<<<512, 256, 0, stream>>>(wc, input, W_out, out_proj);
}

// Round 12
// 25.565 us; speedup vs baseline: 1.6557x; 1.6557x over previous
//
#include <hip/hip_runtime.h>
#include <hip/hip_bf16.h>
#include <math.h>

// Shapes:
//   input [32,1024] f32; source_hids [2048,32,1024] f32 (256 MiB);
//   encoder_padding_mask [2048,32] bool; W_in [1024,1024]; W_out [1024,2048]
// Outputs flat: output [32,1024], beta [2048,32], alpha [2048,32]
//
// Exact simplifications (rounds 1-2):
//   alpha = p * exclusive_cumprod(1-p); beta = alpha.
//   f32: sigmoid(e)==1.0f exactly for e >~ 17.3 => (1-p)==0.0f => running
//   cumprod hits EXACT 0 => all later beta exactly 0 regardless of p.
//   => energy/scan only for s < CH=64; tails pre-zeroed; exact sequential
//   fallback (P ~ 1e-9) finishes a non-collapsed column.
//
// Round-12 = R7 structure (proven 30.6us; fusion attempts 0-for-3) with ONE
// unconfounded change: Q=2 batches/wave in both GEMVs at the SAME 2048-wave
// count (8 rows/wave instead of 16). Halves total W streaming (384->192 MB)
// without losing latency-hiding (R6 confounded Q with a 4x wave cut).
// Discriminator: BW-component real -> 25-27us; pure-latency -> unchanged.

#define SRC_LEN 2048
#define BSZ     32
#define DIM     1024
#define CH      64
#define TAIL4   ((SRC_LEN - CH) * BSZ / 4)   // 15872 float4 per tail array

// ---------------- kernel 1: x = input @ W_in^T (Q=2 register GEMV) ----------------
// 512 blocks x 256 thr = 2048 waves; wave -> (batch-pair, 8-row chunk)
__global__ __launch_bounds__(256) void k_xproj(const float* __restrict__ input,
                                               const float* __restrict__ W,
                                               float* __restrict__ x) {
    int wid  = blockIdx.x * 4 + (threadIdx.x >> 6);   // 0..2047
    int lane = threadIdx.x & 63;
    int bp   = wid >> 7;                              // 0..15
    int rc   = wid & 127;                             // 0..127
    int i0   = rc * 8;
    int b0 = bp * 2, b1 = bp * 2 + 1;
    const float4* inp0 = (const float4*)(input + (size_t)b0 * DIM);
    const float4* inp1 = (const float4*)(input + (size_t)b1 * DIM);
    float4 a0[4], a1[4];
    #pragma unroll
    for (int k = 0; k < 4; ++k) {
        a0[k] = inp0[lane + 64 * k];
        a1[k] = inp1[lane + 64 * k];
    }
    #pragma unroll 4
    for (int i = 0; i < 8; ++i) {
        const float4* wr = (const float4*)(W + (size_t)(i0 + i) * DIM);
        float s0 = 0.f, s1 = 0.f;
        #pragma unroll
        for (int k = 0; k < 4; ++k) {
            float4 wv = wr[lane + 64 * k];
            s0 += wv.x * a0[k].x + wv.y * a0[k].y + wv.z * a0[k].z + wv.w * a0[k].w;
            s1 += wv.x * a1[k].x + wv.y * a1[k].y + wv.z * a1[k].z + wv.w * a1[k].w;
        }
        #pragma unroll
        for (int off = 32; off; off >>= 1) {
            s0 += __shfl_down(s0, off);
            s1 += __shfl_down(s1, off);
        }
        if (lane == 0) {
            x[(size_t)b0 * DIM + i0 + i] = s0;
            x[(size_t)b1 * DIM + i0 + i] = s1;
        }
    }
}

// ---------------- kernel 2: energies (s<CH) + tail zero-fill (R7 verbatim) ----------------
__global__ __launch_bounds__(256) void k_energy_fill(const float* __restrict__ src,
                                                     const float* __restrict__ x,
                                                     float* __restrict__ energy,
                                                     float* __restrict__ beta_out,
                                                     float* __restrict__ alpha_out) {
    int bid = blockIdx.x;
    if (bid < 512) {
        int wid  = bid * 4 + (threadIdx.x >> 6);      // 0..2047
        int lane = threadIdx.x & 63;
        int s = wid >> 5, b = wid & (BSZ - 1);
        const float4* row = (const float4*)(src + ((size_t)s * BSZ + b) * DIM);
        const float4* xr  = (const float4*)(x + (size_t)b * DIM);
        float acc = 0.f;
        #pragma unroll
        for (int k = 0; k < 4; ++k) {
            float4 v = row[lane + 64 * k];
            float4 c = xr[lane + 64 * k];
            acc += v.x * c.x + v.y * c.y + v.z * c.z + v.w * c.w;
        }
        #pragma unroll
        for (int off = 32; off; off >>= 1) acc += __shfl_down(acc, off);
        if (lane == 0) energy[(size_t)s * BSZ + b] = acc;
    } else {
        int i = (bid - 512) * 256 + threadIdx.x;
        if (i < TAIL4) {
            float4 z = {0.f, 0.f, 0.f, 0.f};
            ((float4*)(beta_out  + (size_t)CH * BSZ))[i] = z;
            ((float4*)(alpha_out + (size_t)CH * BSZ))[i] = z;
        }
    }
}

// ---------------- kernel 3: scan + wc (+ exact sequential fallback) (R7 verbatim) ----------------
__global__ __launch_bounds__(1024) void k_scan_wc(const float* __restrict__ src,
                                                  const float* __restrict__ x,
                                                  const unsigned char* __restrict__ mask,
                                                  const float* __restrict__ energy,
                                                  float* __restrict__ beta_out,
                                                  float* __restrict__ alpha_out,
                                                  float* __restrict__ wc) {
    int b = blockIdx.x;
    int t = threadIdx.x;
    int w = t >> 6, lane = t & 63;
    __shared__ float pb[CH];
    __shared__ int   snz;      // number of leading rows with beta != 0
    __shared__ float cstate;
    __shared__ float red[16];
    __shared__ float crun, bcur;
    __shared__ __align__(16) float xs[DIM];

    // wave 0: sigmoid + exclusive cumprod scan over s < CH
    if (w == 0) {
        float ev = energy[(size_t)lane * BSZ + b];
        if (mask[(size_t)lane * BSZ + b]) ev = -1e9f;
        float p  = 1.0f / (1.0f + expf(-ev));
        float om = 1.0f - p;
        float prod = om;
        #pragma unroll
        for (int off = 1; off < 64; off <<= 1) {
            float o = __shfl_up(prod, off);
            if (lane >= off) prod *= o;
        }
        float excl = __shfl_up(prod, 1);
        if (lane == 0) excl = 1.0f;
        float a = p * excl;
        beta_out[(size_t)lane * BSZ + b]  = a;
        alpha_out[(size_t)lane * BSZ + b] = a;
        pb[lane] = a;
        unsigned long long nz = __ballot(a != 0.0f);
        if (lane == 0) snz = (nz == 0ULL) ? 0 : (64 - __builtin_clzll(nz));
        if (lane == 63) cstate = prod;
    }
    __syncthreads();

    // weighted context over the nonzero prefix (rows cache-hot)
    float acc = 0.f;                       // thread t owns wc[b, t]
    int smax = snz;
    for (int s = 0; s < smax; ++s) {
        float wgt = pb[s];
        if (wgt != 0.0f) acc += wgt * src[((size_t)s * BSZ + b) * DIM + t];
    }

    // sequential fallback for a non-collapsed column (exact; ~never runs)
    if (cstate != 0.0f) {
        for (int i = t; i < DIM; i += 1024) xs[i] = x[(size_t)b * DIM + i];
        if (t == 0) crun = cstate;
        __syncthreads();
        for (int s = CH; s < SRC_LEN; ++s) {
            float v = src[((size_t)s * BSZ + b) * DIM + t];
            float part = v * xs[t];
            #pragma unroll
            for (int off = 32; off; off >>= 1) part += __shfl_down(part, off);
            if (lane == 0) red[w] = part;
            __syncthreads();
            if (t == 0) {
                float ev = 0.f;
                #pragma unroll
                for (int i = 0; i < 16; ++i) ev += red[i];
                if (mask[(size_t)s * BSZ + b]) ev = -1e9f;
                float p = 1.0f / (1.0f + expf(-ev));
                float a = p * crun;
                beta_out[(size_t)s * BSZ + b]  = a;
                alpha_out[(size_t)s * BSZ + b] = a;
                bcur = a;
                crun = crun * (1.0f - p);
            }
            __syncthreads();
            acc += bcur * v;
            if (crun == 0.0f) break;
        }
    }

    wc[(size_t)b * DIM + t] = acc;
}

// ---------------- kernel 4: out = tanh([wc, input] @ W_out^T) (Q=2 register GEMV) ----------------
// 512 blocks x 256 thr = 2048 waves; wave -> (batch-pair, 8-o-row chunk)
__global__ __launch_bounds__(256) void k_out(const float* __restrict__ wc,
                                             const float* __restrict__ input,
                                             const float* __restrict__ W,
                                             float* __restrict__ out) {
    int wid  = blockIdx.x * 4 + (threadIdx.x >> 6);   // 0..2047
    int lane = threadIdx.x & 63;
    int bp   = wid >> 7;                              // 0..15
    int oc   = wid & 127;                             // 0..127
    int o0   = oc * 8;
    int b0 = bp * 2, b1 = bp * 2 + 1;
    const float4* wc0 = (const float4*)(wc    + (size_t)b0 * DIM);
    const float4* wc1 = (const float4*)(wc    + (size_t)b1 * DIM);
    const float4* in0 = (const float4*)(input + (size_t)b0 * DIM);
    const float4* in1 = (const float4*)(input + (size_t)b1 * DIM);
    float4 c0[4], c1[4], u0[4], u1[4];
    #pragma unroll
    for (int k = 0; k < 4; ++k) {
        c0[k] = wc0[lane + 64 * k]; c1[k] = wc1[lane + 64 * k];
        u0[k] = in0[lane + 64 * k]; u1[k] = in1[lane + 64 * k];
    }
    #pragma unroll 2
    for (int i = 0; i < 8; ++i) {
        const float4* wr = (const float4*)(W + (size_t)(o0 + i) * 2 * DIM);
        float s0 = 0.f, s1 = 0.f;
        #pragma unroll
        for (int k = 0; k < 4; ++k) {
            float4 wv = wr[lane + 64 * k];            // pairs with wc part
            s0 += wv.x * c0[k].x + wv.y * c0[k].y + wv.z * c0[k].z + wv.w * c0[k].w;
            s1 += wv.x * c1[k].x + wv.y * c1[k].y + wv.z * c1[k].z + wv.w * c1[k].w;
        }
        #pragma unroll
        for (int k = 0; k < 4; ++k) {
            float4 wv = wr[256 + lane + 64 * k];      // pairs with input part
            s0 += wv.x * u0[k].x + wv.y * u0[k].y + wv.z * u0[k].z + wv.w * u0[k].w;
            s1 += wv.x * u1[k].x + wv.y * u1[k].y + wv.z * u1[k].z + wv.w * u1[k].w;
        }
        #pragma unroll
        for (int off = 32; off; off >>= 1) {
            s0 += __shfl_down(s0, off);
            s1 += __shfl_down(s1, off);
        }
        if (lane == 0) {
            out[(size_t)b0 * DIM + o0 + i] = tanhf(s0);
            out[(size_t)b1 * DIM + o0 + i] = tanhf(s1);
        }
    }
}

extern "C" void kernel_launch(void* const* d_in, const int* in_sizes, int n_in,
                              void* d_out, int out_size, void* d_ws, size_t ws_size,
                              hipStream_t stream) {
    const float* input = (const float*)d_in[0];
    const float* src   = (const float*)d_in[1];
    const unsigned char* mask = (const unsigned char*)d_in[2];
    const float* W_in  = (const float*)d_in[3];
    const float* W_out = (const float*)d_in[4];

    float* out_proj  = (float*)d_out;                 // [32,1024]
    float* beta_out  = out_proj + BSZ * DIM;          // [2048,32]
    float* alpha_out = beta_out + SRC_LEN * BSZ;      // [2048,32]

    float* ws = (float*)d_ws;
    float* x      = ws;                    // 32768 floats
    float* wc     = x + BSZ * DIM;         // 32768 floats
    float* energy = wc + BSZ * DIM;        // 2048 floats

    k_xproj<<<512, 256, 0, stream>>>(input, W_in, x);
    k_energy_fill<<<512 + 64, 256, 0, stream>>>(src, x, energy, beta_out, alpha_out);
    k_scan_wc<<<BSZ, 1024, 0, stream>>>(src, x, mask, energy, beta_out, alpha_out, wc);
    k_out<<<512, 256, 0, stream>>>(wc, input, W_out, out_proj);
}